// Round 1
// baseline (355.080 us; speedup 1.0000x reference)
//
#include <hip/hip_runtime.h>

typedef unsigned short u16;
typedef __bf16 bf16;
typedef float f32x4 __attribute__((ext_vector_type(4)));
typedef bf16 bf16x8 __attribute__((ext_vector_type(8)));
typedef short s16x4 __attribute__((ext_vector_type(4)));
typedef u16 u16x4 __attribute__((ext_vector_type(4)));

#define SEQ 2048
#define DIN 2048
#define NH 32
#define NKV 8
#define HD 64

__device__ __forceinline__ u16 f2bf(float f) {
    return __builtin_bit_cast(u16, (bf16)f);
}

// ---------------- cast f32 -> bf16 (vectorized) ----------------
__global__ __launch_bounds__(256) void cast_bf16_k(const float* __restrict__ in,
                                                   u16* __restrict__ out, int n4) {
    int i = blockIdx.x * 256 + threadIdx.x;
    int stride = gridDim.x * 256;
    for (; i < n4; i += stride) {
        float4 v = reinterpret_cast<const float4*>(in)[i];
        u16x4 o;
        o[0] = f2bf(v.x); o[1] = f2bf(v.y); o[2] = f2bf(v.z); o[3] = f2bf(v.w);
        reinterpret_cast<u16x4*>(out)[i] = o;
    }
}

// ---------------- transpose + cast: src f32 [R][C] -> dst bf16 [C][R] ----------------
__global__ __launch_bounds__(256) void transpose_cast_k(const float* __restrict__ src,
                                                        u16* __restrict__ dst, int R, int C) {
    __shared__ float t[64][65];
    int c0 = blockIdx.x * 64, r0 = blockIdx.y * 64;
    int tx = threadIdx.x & 63, ty = threadIdx.x >> 6;
#pragma unroll
    for (int i = 0; i < 16; ++i) {
        int r = ty + i * 4;
        t[r][tx] = src[(size_t)(r0 + r) * C + c0 + tx];
    }
    __syncthreads();
#pragma unroll
    for (int i = 0; i < 16; ++i) {
        int c = ty + i * 4;
        dst[(size_t)(c0 + c) * R + r0 + tx] = f2bf(t[tx][c]);
    }
}

// ---------------- GEMM: C[M,N] = A[M,K] @ Bt[N,K]^T, bf16 in, f32 out ----------------
// 128x128 tile, BK=32, 4 waves (2x2 of 64x64), global_load_lds staging (m97 structure)
__global__ __launch_bounds__(256) void gemm_bt_k(const u16* __restrict__ A,
                                                 const u16* __restrict__ Bt,
                                                 float* __restrict__ C,
                                                 int M, int N, int K) {
    __shared__ __align__(16) u16 As[128 * 32];
    __shared__ __align__(16) u16 Bs[128 * 32];
    int tid = threadIdx.x;
    int wave = tid >> 6, lane = tid & 63;
    int bm = blockIdx.y * 128, bn = blockIdx.x * 128;
    int wm = (wave >> 1) * 64, wn = (wave & 1) * 64;
    int g = lane >> 4, cidx = lane & 15;
    f32x4 acc[4][4] = {};

    // staging geometry: chunk = wave*2+j covers LDS elements [chunk*512, +512)
    // lane covers row chunk*16 + (lane>>2), k = (lane&3)*8  (16B contiguous)
    int srow = (lane >> 2);
    int skol = (lane & 3) * 8;

    for (int kt = 0; kt < K; kt += 32) {
#pragma unroll
        for (int j = 0; j < 2; ++j) {
            const u16* gp = A + (size_t)(bm + (wave * 2 + j) * 16 + srow) * K + kt + skol;
            __builtin_amdgcn_global_load_lds(
                (__attribute__((address_space(1))) void*)gp,
                (__attribute__((address_space(3))) void*)&As[(wave * 2 + j) * 512],
                16, 0, 0);
        }
#pragma unroll
        for (int j = 0; j < 2; ++j) {
            const u16* gp = Bt + (size_t)(bn + (wave * 2 + j) * 16 + srow) * K + kt + skol;
            __builtin_amdgcn_global_load_lds(
                (__attribute__((address_space(1))) void*)gp,
                (__attribute__((address_space(3))) void*)&Bs[(wave * 2 + j) * 512],
                16, 0, 0);
        }
        asm volatile("s_waitcnt vmcnt(0)" ::: "memory");
        __syncthreads();

        bf16x8 af[4], bfr[4];
#pragma unroll
        for (int mi = 0; mi < 4; ++mi)
            af[mi] = *reinterpret_cast<const bf16x8*>(&As[(wm + mi * 16 + cidx) * 32 + g * 8]);
#pragma unroll
        for (int ni = 0; ni < 4; ++ni)
            bfr[ni] = *reinterpret_cast<const bf16x8*>(&Bs[(wn + ni * 16 + cidx) * 32 + g * 8]);
#pragma unroll
        for (int mi = 0; mi < 4; ++mi)
#pragma unroll
            for (int ni = 0; ni < 4; ++ni)
                acc[mi][ni] = __builtin_amdgcn_mfma_f32_16x16x32_bf16(af[mi], bfr[ni], acc[mi][ni], 0, 0, 0);
        __syncthreads();
    }

#pragma unroll
    for (int mi = 0; mi < 4; ++mi) {
#pragma unroll
        for (int r = 0; r < 4; ++r) {
            int row = bm + wm + mi * 16 + g * 4 + r;
            float* cp = C + (size_t)row * N + bn + wn + cidx;
#pragma unroll
            for (int ni = 0; ni < 4; ++ni)
                cp[ni * 16] = acc[mi][ni][r];
        }
    }
}

// ---------------- RMSNorm + RoPE for Q and K heads ----------------
// qkv: f32 [2048][3072] (q: 0..2047, k: 2048..2559, v: 2560..3071)
// one wave per (s, hh); hh<32: q head, hh>=32: k head (hh-32)
__global__ __launch_bounds__(256) void norm_rope_k(const float* __restrict__ qkv,
                                                   const float* __restrict__ cosb,
                                                   const float* __restrict__ sinb,
                                                   const float* __restrict__ qw,
                                                   const float* __restrict__ kw,
                                                   u16* __restrict__ qn,
                                                   u16* __restrict__ kn) {
    int idx = blockIdx.x * 4 + (threadIdx.x >> 6);
    int lane = threadIdx.x & 63;
    int s = idx / 40, hh = idx - s * 40;
    float val;
    if (hh < 32) val = qkv[(size_t)s * 3072 + hh * 64 + lane];
    else         val = qkv[(size_t)s * 3072 + 2048 + (hh - 32) * 64 + lane];
    float ss = val * val;
#pragma unroll
    for (int mm = 32; mm; mm >>= 1) ss += __shfl_xor(ss, mm);
    float w = (hh < 32) ? qw[lane] : kw[lane];
    float xn = val * rsqrtf(ss * (1.f / 64.f) + 1e-6f) * w;
    float part = __shfl_xor(xn, 32);
    float rot = (lane < 32) ? -part : part;
    float o = xn * cosb[s * 64 + lane] + rot * sinb[s * 64 + lane];
    u16 ob = f2bf(o);
    if (hh < 32) qn[(size_t)s * 2048 + hh * 64 + lane] = ob;
    else         kn[(size_t)s * 512 + (hh - 32) * 64 + lane] = ob;
}

// ---------------- V transpose: qkv cols [2560..3072) -> vt[kvh][d][s] bf16 ----------------
__global__ __launch_bounds__(256) void v_transpose_k(const float* __restrict__ qkv,
                                                     u16* __restrict__ vt) {
    __shared__ float t[64][65];
    int s0 = blockIdx.x * 64;
    int h = blockIdx.y;
    int tx = threadIdx.x & 63, ty = threadIdx.x >> 6;
#pragma unroll
    for (int i = 0; i < 16; ++i) {
        int r = ty + i * 4;
        t[r][tx] = qkv[(size_t)(s0 + r) * 3072 + 2560 + h * 64 + tx];
    }
    __syncthreads();
#pragma unroll
    for (int i = 0; i < 16; ++i) {
        int dd = ty + i * 4;
        vt[((size_t)h * 64 + dd) * 2048 + s0 + tx] = f2bf(t[tx][dd]);
    }
}

// ---------------- Flash attention with sink (swapped QK^T) ----------------
// grid: (32 heads, 32 q-chunks of 64); each wave owns 16 q rows.
// S^T = mfma(K_frag, Q_frag): D row=(lane>>4)*4+reg = key, col=lane&15 = q.
// PV: out^T = mfma_16x16x16(V^T_frag, P^T_frag): P^T B-operand layout == S^T D layout.
__global__ __launch_bounds__(256) void attn_k(const u16* __restrict__ qn,
                                              const u16* __restrict__ kn,
                                              const u16* __restrict__ vt,
                                              const float* __restrict__ sink,
                                              u16* __restrict__ attn) {
    int h = blockIdx.x;
    int wave = threadIdx.x >> 6, lane = threadIdx.x & 63;
    int q0 = blockIdx.y * 64 + wave * 16;
    int kvh = h >> 2;
    int g = lane >> 4, c = lane & 15;
    int qrow = q0 + c;

    const size_t qoff = (size_t)(q0 + c) * 2048 + h * 64;
    bf16x8 qf0 = *reinterpret_cast<const bf16x8*>(&qn[qoff + g * 8]);
    bf16x8 qf1 = *reinterpret_cast<const bf16x8*>(&qn[qoff + 32 + g * 8]);

    float m = sink[h];   // sink as virtual key: l starts at exp(sink-m)=1
    float l = 1.f;
    f32x4 o[4] = {};

    const u16* kbase = kn + kvh * 64;
    const u16* vbase = vt + (size_t)kvh * 64 * 2048;
    int nk = q0 + 16;

    for (int kv0 = 0; kv0 < nk; kv0 += 64) {
        float pv[16];
#pragma unroll
        for (int sub = 0; sub < 4; ++sub) {
            int krow = kv0 + sub * 16 + c;
            const u16* kp = kbase + (size_t)krow * 512;
            bf16x8 kf0 = *reinterpret_cast<const bf16x8*>(kp + g * 8);
            bf16x8 kf1 = *reinterpret_cast<const bf16x8*>(kp + 32 + g * 8);
            f32x4 st = __builtin_amdgcn_mfma_f32_16x16x32_bf16(kf0, qf0, (f32x4){0.f, 0.f, 0.f, 0.f}, 0, 0, 0);
            st = __builtin_amdgcn_mfma_f32_16x16x32_bf16(kf1, qf1, st, 0, 0, 0);
#pragma unroll
            for (int r = 0; r < 4; ++r) {
                int key = kv0 + sub * 16 + g * 4 + r;
                float sc = st[r] * 0.125f;
                pv[sub * 4 + r] = (key > qrow) ? -1e30f : sc;
            }
        }
        // online softmax (stats per q-column c; reduce across groups via shfl 16/32)
        float bmax = pv[0];
#pragma unroll
        for (int i = 1; i < 16; ++i) bmax = fmaxf(bmax, pv[i]);
        bmax = fmaxf(bmax, __shfl_xor(bmax, 16));
        bmax = fmaxf(bmax, __shfl_xor(bmax, 32));
        float mn = fmaxf(m, bmax);
        float corr = __expf(m - mn);
        m = mn;
        float rs = 0.f;
#pragma unroll
        for (int i = 0; i < 16; ++i) { pv[i] = __expf(pv[i] - mn); rs += pv[i]; }
        rs += __shfl_xor(rs, 16);
        rs += __shfl_xor(rs, 32);
        l = l * corr + rs;
#pragma unroll
        for (int dt = 0; dt < 4; ++dt) {
            o[dt][0] *= corr; o[dt][1] *= corr; o[dt][2] *= corr; o[dt][3] *= corr;
        }
        // PV: per 16-key subtile, 4 d-tiles of 16
#pragma unroll
        for (int sub = 0; sub < 4; ++sub) {
            s16x4 pf;
#pragma unroll
            for (int i = 0; i < 4; ++i) pf[i] = (short)f2bf(pv[sub * 4 + i]);
            const u16* vp0 = vbase + kv0 + sub * 16 + g * 4;
#pragma unroll
            for (int dt = 0; dt < 4; ++dt) {
                s16x4 vf = *reinterpret_cast<const s16x4*>(vp0 + (size_t)(dt * 16 + c) * 2048);
                o[dt] = __builtin_amdgcn_mfma_f32_16x16x16bf16_1k(vf, pf, o[dt], 0, 0, 0);
            }
        }
    }

    float inv = 1.f / l;
#pragma unroll
    for (int dt = 0; dt < 4; ++dt) {
        u16x4 ov;
#pragma unroll
        for (int r = 0; r < 4; ++r) ov[r] = f2bf(o[dt][r] * inv);
        *reinterpret_cast<u16x4*>(&attn[(size_t)qrow * 2048 + h * 64 + dt * 16 + g * 4]) = ov;
    }
}

extern "C" void kernel_launch(void* const* d_in, const int* in_sizes, int n_in,
                              void* d_out, int out_size, void* d_ws, size_t ws_size,
                              hipStream_t stream) {
    const float* x    = (const float*)d_in[0];
    // d_in[1] = mask (causal, computed analytically)
    const float* cosb = (const float*)d_in[2];
    const float* sinb = (const float*)d_in[3];
    const float* wq   = (const float*)d_in[4];
    const float* wk   = (const float*)d_in[5];
    const float* wv   = (const float*)d_in[6];
    const float* wo   = (const float*)d_in[7];
    const float* qw   = (const float*)d_in[8];
    const float* kw   = (const float*)d_in[9];
    const float* sink = (const float*)d_in[10];
    float* out = (float*)d_out;

    char* ws = (char*)d_ws;
    size_t off = 0;
    auto alloc = [&](size_t bytes) {
        char* p = ws + off;
        off += (bytes + 255) & ~(size_t)255;
        return p;
    };
    u16*   xb    = (u16*)alloc((size_t)2048 * 2048 * 2);   // x bf16
    u16*   wqkvt = (u16*)alloc((size_t)3072 * 2048 * 2);   // [wq^T; wk^T; wv^T]
    u16*   wot   = (u16*)alloc((size_t)2048 * 2048 * 2);   // wo^T
    float* qkv   = (float*)alloc((size_t)2048 * 3072 * 4); // raw q|k|v f32
    u16*   qnb   = (u16*)alloc((size_t)2048 * 2048 * 2);   // q normed+roped
    u16*   knb   = (u16*)alloc((size_t)2048 * 512 * 2);    // k normed+roped
    u16*   vtb   = (u16*)alloc((size_t)8 * 64 * 2048 * 2); // v^T per kv head
    u16*   attnb = xb;                                      // reuse (xb dead after GEMM1)

    cast_bf16_k<<<2048, 256, 0, stream>>>(x, xb, 2048 * 2048 / 4);
    transpose_cast_k<<<dim3(32, 32), 256, 0, stream>>>(wq, wqkvt, 2048, 2048);
    transpose_cast_k<<<dim3(8, 32), 256, 0, stream>>>(wk, wqkvt + (size_t)2048 * 2048, 2048, 512);
    transpose_cast_k<<<dim3(8, 32), 256, 0, stream>>>(wv, wqkvt + (size_t)2560 * 2048, 2048, 512);
    transpose_cast_k<<<dim3(32, 32), 256, 0, stream>>>(wo, wot, 2048, 2048);

    gemm_bt_k<<<dim3(24, 16), 256, 0, stream>>>(xb, wqkvt, qkv, 2048, 3072, 2048);
    norm_rope_k<<<20480, 256, 0, stream>>>(qkv, cosb, sinb, qw, kw, qnb, knb);
    v_transpose_k<<<dim3(32, 8), 256, 0, stream>>>(qkv, vtb);
    attn_k<<<dim3(32, 32), 256, 0, stream>>>(qnb, knb, vtb, sink, attnb);
    gemm_bt_k<<<dim3(16, 16), 256, 0, stream>>>(attnb, wot, out, 2048, 2048, 2048);
}

// Round 2
// 303.026 us; speedup vs baseline: 1.1718x; 1.1718x over previous
//
#include <hip/hip_runtime.h>

typedef unsigned short u16;
typedef __bf16 bf16;
typedef float f32x4 __attribute__((ext_vector_type(4)));
typedef bf16 bf16x8 __attribute__((ext_vector_type(8)));
typedef short s16x4 __attribute__((ext_vector_type(4)));
typedef u16 u16x4 __attribute__((ext_vector_type(4)));

#define SEQ 2048
#define DIN 2048
#define NH 32
#define NKV 8
#define HD 64

__device__ __forceinline__ u16 f2bf(float f) {
    return __builtin_bit_cast(u16, (bf16)f);
}

// ---------------- cast f32 -> bf16 (vectorized) ----------------
__global__ __launch_bounds__(256) void cast_bf16_k(const float* __restrict__ in,
                                                   u16* __restrict__ out, int n4) {
    int i = blockIdx.x * 256 + threadIdx.x;
    int stride = gridDim.x * 256;
    for (; i < n4; i += stride) {
        float4 v = reinterpret_cast<const float4*>(in)[i];
        u16x4 o;
        o[0] = f2bf(v.x); o[1] = f2bf(v.y); o[2] = f2bf(v.z); o[3] = f2bf(v.w);
        reinterpret_cast<u16x4*>(out)[i] = o;
    }
}

// ---------------- transpose + cast: src f32 [R][C] -> dst bf16 [C][R] ----------------
__global__ __launch_bounds__(256) void transpose_cast_k(const float* __restrict__ src,
                                                        u16* __restrict__ dst, int R, int C) {
    __shared__ float t[64][65];
    int c0 = blockIdx.x * 64, r0 = blockIdx.y * 64;
    int tx = threadIdx.x & 63, ty = threadIdx.x >> 6;
#pragma unroll
    for (int i = 0; i < 16; ++i) {
        int r = ty + i * 4;
        t[r][tx] = src[(size_t)(r0 + r) * C + c0 + tx];
    }
    __syncthreads();
#pragma unroll
    for (int i = 0; i < 16; ++i) {
        int c = ty + i * 4;
        dst[(size_t)(c0 + c) * R + r0 + tx] = f2bf(t[tx][c]);
    }
}

// ---------------- GEMM: C[M,N] = A[M,K] @ Bt[N,K]^T, bf16 in, f32 out ----------------
__global__ __launch_bounds__(256) void gemm_bt_k(const u16* __restrict__ A,
                                                 const u16* __restrict__ Bt,
                                                 float* __restrict__ C,
                                                 int M, int N, int K) {
    __shared__ __align__(16) u16 As[128 * 32];
    __shared__ __align__(16) u16 Bs[128 * 32];
    int tid = threadIdx.x;
    int wave = tid >> 6, lane = tid & 63;
    int bm = blockIdx.y * 128, bn = blockIdx.x * 128;
    int wm = (wave >> 1) * 64, wn = (wave & 1) * 64;
    int g = lane >> 4, cidx = lane & 15;
    f32x4 acc[4][4] = {};

    int srow = (lane >> 2);
    int skol = (lane & 3) * 8;

    for (int kt = 0; kt < K; kt += 32) {
#pragma unroll
        for (int j = 0; j < 2; ++j) {
            const u16* gp = A + (size_t)(bm + (wave * 2 + j) * 16 + srow) * K + kt + skol;
            __builtin_amdgcn_global_load_lds(
                (__attribute__((address_space(1))) void*)gp,
                (__attribute__((address_space(3))) void*)&As[(wave * 2 + j) * 512],
                16, 0, 0);
        }
#pragma unroll
        for (int j = 0; j < 2; ++j) {
            const u16* gp = Bt + (size_t)(bn + (wave * 2 + j) * 16 + srow) * K + kt + skol;
            __builtin_amdgcn_global_load_lds(
                (__attribute__((address_space(1))) void*)gp,
                (__attribute__((address_space(3))) void*)&Bs[(wave * 2 + j) * 512],
                16, 0, 0);
        }
        asm volatile("s_waitcnt vmcnt(0)" ::: "memory");
        __syncthreads();

        bf16x8 af[4], bfr[4];
#pragma unroll
        for (int mi = 0; mi < 4; ++mi)
            af[mi] = *reinterpret_cast<const bf16x8*>(&As[(wm + mi * 16 + cidx) * 32 + g * 8]);
#pragma unroll
        for (int ni = 0; ni < 4; ++ni)
            bfr[ni] = *reinterpret_cast<const bf16x8*>(&Bs[(wn + ni * 16 + cidx) * 32 + g * 8]);
#pragma unroll
        for (int mi = 0; mi < 4; ++mi)
#pragma unroll
            for (int ni = 0; ni < 4; ++ni)
                acc[mi][ni] = __builtin_amdgcn_mfma_f32_16x16x32_bf16(af[mi], bfr[ni], acc[mi][ni], 0, 0, 0);
        __syncthreads();
    }

#pragma unroll
    for (int mi = 0; mi < 4; ++mi) {
#pragma unroll
        for (int r = 0; r < 4; ++r) {
            int row = bm + wm + mi * 16 + g * 4 + r;
            float* cp = C + (size_t)row * N + bn + wn + cidx;
#pragma unroll
            for (int ni = 0; ni < 4; ++ni)
                cp[ni * 16] = acc[mi][ni][r];
        }
    }
}

// ---------------- RMSNorm + RoPE for Q and K heads ----------------
// Q: pre-scaled by 0.125 (= HEAD_DIM^-0.5, exact power of 2), row-major [s][32*64]
// K: written in MFMA A-fragment order kfrag[kvh][kb=s>>4][g=d>>3][c=s&15][e=d&7]
__global__ __launch_bounds__(256) void norm_rope_k(const float* __restrict__ qkv,
                                                   const float* __restrict__ cosb,
                                                   const float* __restrict__ sinb,
                                                   const float* __restrict__ qw,
                                                   const float* __restrict__ kw,
                                                   u16* __restrict__ qn,
                                                   u16* __restrict__ kfrag) {
    int idx = blockIdx.x * 4 + (threadIdx.x >> 6);
    int lane = threadIdx.x & 63;
    int s = idx / 40, hh = idx - s * 40;
    float val;
    if (hh < 32) val = qkv[(size_t)s * 3072 + hh * 64 + lane];
    else         val = qkv[(size_t)s * 3072 + 2048 + (hh - 32) * 64 + lane];
    float ss = val * val;
#pragma unroll
    for (int mm = 32; mm; mm >>= 1) ss += __shfl_xor(ss, mm);
    float w = (hh < 32) ? qw[lane] : kw[lane];
    float xn = val * rsqrtf(ss * (1.f / 64.f) + 1e-6f) * w;
    float part = __shfl_xor(xn, 32);
    float rot = (lane < 32) ? -part : part;
    float o = xn * cosb[s * 64 + lane] + rot * sinb[s * 64 + lane];
    if (hh < 32) {
        qn[(size_t)s * 2048 + hh * 64 + lane] = f2bf(o * 0.125f);
    } else {
        int h8 = hh - 32;
        kfrag[(((size_t)h8 * 128 + (s >> 4)) << 10) + (lane >> 3) * 128 + (s & 15) * 8 + (lane & 7)] = f2bf(o);
    }
}

// ---------------- V in PV A-fragment order ----------------
// vfrag[kvh][kb][dt][g][c][i] = V[kb*16 + g*4 + i][dt*16 + c]
__global__ __launch_bounds__(256) void v_frag_k(const float* __restrict__ qkv,
                                                u16* __restrict__ vfrag) {
    __shared__ float t[64][65];
    int s0 = blockIdx.x * 64;
    int h = blockIdx.y;
    int tx = threadIdx.x & 63, ty = threadIdx.x >> 6;
#pragma unroll
    for (int i = 0; i < 16; ++i) {
        int r = ty + i * 4;
        t[r][tx] = qkv[(size_t)(s0 + r) * 3072 + 2560 + h * 64 + tx];
    }
    __syncthreads();
    int dt = threadIdx.x >> 6, g = (threadIdx.x >> 4) & 3, c = threadIdx.x & 15;
#pragma unroll
    for (int kb2 = 0; kb2 < 4; ++kb2) {
        u16x4 o;
#pragma unroll
        for (int i = 0; i < 4; ++i) o[i] = f2bf(t[kb2 * 16 + g * 4 + i][dt * 16 + c]);
        *reinterpret_cast<u16x4*>(
            &vfrag[(((size_t)h * 128 + (s0 >> 4) + kb2) << 10) + dt * 256 + g * 64 + c * 4]) = o;
    }
}

// ---------------- online-softmax update for one stream (no PV) ----------------
__device__ __forceinline__ void softmax_part(f32x4 (&st)[4], float& m, float& l,
                                             f32x4 (&o)[4], int qrow, int key0g, bool domask) {
    if (domask) {
#pragma unroll
        for (int sub = 0; sub < 4; ++sub)
#pragma unroll
            for (int r = 0; r < 4; ++r)
                if (key0g + sub * 16 + r > qrow) st[sub][r] = -1e30f;
    }
    float m01 = fmaxf(fmaxf(st[0][0], st[0][1]), fmaxf(st[0][2], st[0][3]));
    float m23 = fmaxf(fmaxf(st[1][0], st[1][1]), fmaxf(st[1][2], st[1][3]));
    float m45 = fmaxf(fmaxf(st[2][0], st[2][1]), fmaxf(st[2][2], st[2][3]));
    float m67 = fmaxf(fmaxf(st[3][0], st[3][1]), fmaxf(st[3][2], st[3][3]));
    float bmax = fmaxf(fmaxf(m01, m23), fmaxf(m45, m67));
    bmax = fmaxf(bmax, __shfl_xor(bmax, 16));
    bmax = fmaxf(bmax, __shfl_xor(bmax, 32));
    if (!__all(bmax <= m)) {   // exact skip: when no lane's max grows, corr==1
        float mn = fmaxf(m, bmax);
        float corr = __expf(m - mn);
        m = mn;
        l *= corr;
#pragma unroll
        for (int dt = 0; dt < 4; ++dt) {
            o[dt][0] *= corr; o[dt][1] *= corr; o[dt][2] *= corr; o[dt][3] *= corr;
        }
    }
    float rs = 0.f;
#pragma unroll
    for (int sub = 0; sub < 4; ++sub)
#pragma unroll
        for (int r = 0; r < 4; ++r) {
            float e = __expf(st[sub][r] - m);
            st[sub][r] = e;
            rs += e;
        }
    rs += __shfl_xor(rs, 16);
    rs += __shfl_xor(rs, 32);
    l += rs;
}

// ---------------- Flash attention with sink: dual-stream balanced waves ----------------
// grid (32 heads, 32); block = 128 threads = 2 waves.
// Wave handles 16 q-rows of a low chunk (A) and 16 of a mirrored high chunk (B):
// every wave processes exactly 33 key-blocks -> uniform work; K/V loads shared.
__global__ __launch_bounds__(128) void attn_k(const u16* __restrict__ qn,
                                              const u16* __restrict__ kfrag,
                                              const u16* __restrict__ vfrag,
                                              const float* __restrict__ sink,
                                              u16* __restrict__ attn) {
    int h = blockIdx.x;
    int b = blockIdx.y;
    int wave = threadIdx.x >> 6, lane = threadIdx.x & 63;
    int kvh = h >> 2;
    int g = lane >> 4, c = lane & 15;
    int q0A = b * 32 + wave * 16;
    int q0B = 2016 - b * 32 + wave * 16;
    int qrowA = q0A + c, qrowB = q0B + c;

    const size_t qoffA = (size_t)qrowA * 2048 + h * 64;
    const size_t qoffB = (size_t)qrowB * 2048 + h * 64;
    bf16x8 qa0 = *reinterpret_cast<const bf16x8*>(&qn[qoffA + g * 8]);
    bf16x8 qa1 = *reinterpret_cast<const bf16x8*>(&qn[qoffA + 32 + g * 8]);
    bf16x8 qb0 = *reinterpret_cast<const bf16x8*>(&qn[qoffB + g * 8]);
    bf16x8 qb1 = *reinterpret_cast<const bf16x8*>(&qn[qoffB + 32 + g * 8]);

    float sk = sink[h];
    float mA = sk, lA = 1.f, mB = sk, lB = 1.f;
    f32x4 oA[4] = {}, oB[4] = {};

    const u16* kbase = kfrag + (((size_t)kvh * 128) << 10) + lane * 8;
    const u16* vbase = vfrag + (((size_t)kvh * 128) << 10) + lane * 4;

    int nkA = q0A + 16, nkB = q0B + 16;

    // preload K for kv0 = 0
    bf16x8 kf0[4], kf1[4];
#pragma unroll
    for (int sub = 0; sub < 4; ++sub) {
        kf0[sub] = *reinterpret_cast<const bf16x8*>(kbase + sub * 1024);
        kf1[sub] = *reinterpret_cast<const bf16x8*>(kbase + sub * 1024 + 512);
    }

#pragma unroll 1
    for (int kv0 = 0; kv0 < nkB; kv0 += 64) {
        bool doA = kv0 < nkA;
        f32x4 stA[4], stB[4];
        __builtin_amdgcn_s_setprio(1);
#pragma unroll
        for (int sub = 0; sub < 4; ++sub) {
            stB[sub] = __builtin_amdgcn_mfma_f32_16x16x32_bf16(kf0[sub], qb0, (f32x4){0.f, 0.f, 0.f, 0.f}, 0, 0, 0);
            stB[sub] = __builtin_amdgcn_mfma_f32_16x16x32_bf16(kf1[sub], qb1, stB[sub], 0, 0, 0);
        }
        if (doA) {
#pragma unroll
            for (int sub = 0; sub < 4; ++sub) {
                stA[sub] = __builtin_amdgcn_mfma_f32_16x16x32_bf16(kf0[sub], qa0, (f32x4){0.f, 0.f, 0.f, 0.f}, 0, 0, 0);
                stA[sub] = __builtin_amdgcn_mfma_f32_16x16x32_bf16(kf1[sub], qa1, stA[sub], 0, 0, 0);
            }
        }
        __builtin_amdgcn_s_setprio(0);

        // register prefetch of next K block (crosses the back-edge)
        if (kv0 + 64 < nkB) {
            const u16* kp = kbase + ((size_t)((kv0 + 64) >> 4) << 10);
#pragma unroll
            for (int sub = 0; sub < 4; ++sub) {
                kf0[sub] = *reinterpret_cast<const bf16x8*>(kp + sub * 1024);
                kf1[sub] = *reinterpret_cast<const bf16x8*>(kp + sub * 1024 + 512);
            }
        }

        int key0g = kv0 + g * 4;
        softmax_part(stB, mB, lB, oB, qrowB, key0g, kv0 + 63 > q0B);
        if (doA) softmax_part(stA, mA, lA, oA, qrowA, key0g, kv0 + 63 > q0A);

        // joint PV: V fragments shared between streams
        const u16* vp = vbase + ((size_t)(kv0 >> 4) << 10);
        __builtin_amdgcn_s_setprio(1);
#pragma unroll
        for (int sub = 0; sub < 4; ++sub) {
            s16x4 pfB, pfA;
#pragma unroll
            for (int i = 0; i < 4; ++i) pfB[i] = (short)f2bf(stB[sub][i]);
            if (doA) {
#pragma unroll
                for (int i = 0; i < 4; ++i) pfA[i] = (short)f2bf(stA[sub][i]);
            }
#pragma unroll
            for (int dt = 0; dt < 4; ++dt) {
                s16x4 vf = *reinterpret_cast<const s16x4*>(vp + sub * 1024 + dt * 256);
                oB[dt] = __builtin_amdgcn_mfma_f32_16x16x16bf16_1k(vf, pfB, oB[dt], 0, 0, 0);
                if (doA) oA[dt] = __builtin_amdgcn_mfma_f32_16x16x16bf16_1k(vf, pfA, oA[dt], 0, 0, 0);
            }
        }
        __builtin_amdgcn_s_setprio(0);
    }

    float invA = 1.f / lA, invB = 1.f / lB;
#pragma unroll
    for (int dt = 0; dt < 4; ++dt) {
        u16x4 ovA, ovB;
#pragma unroll
        for (int r = 0; r < 4; ++r) {
            ovA[r] = f2bf(oA[dt][r] * invA);
            ovB[r] = f2bf(oB[dt][r] * invB);
        }
        *reinterpret_cast<u16x4*>(&attn[(size_t)qrowA * 2048 + h * 64 + dt * 16 + g * 4]) = ovA;
        *reinterpret_cast<u16x4*>(&attn[(size_t)qrowB * 2048 + h * 64 + dt * 16 + g * 4]) = ovB;
    }
}

extern "C" void kernel_launch(void* const* d_in, const int* in_sizes, int n_in,
                              void* d_out, int out_size, void* d_ws, size_t ws_size,
                              hipStream_t stream) {
    const float* x    = (const float*)d_in[0];
    const float* cosb = (const float*)d_in[2];
    const float* sinb = (const float*)d_in[3];
    const float* wq   = (const float*)d_in[4];
    const float* wk   = (const float*)d_in[5];
    const float* wv   = (const float*)d_in[6];
    const float* wo   = (const float*)d_in[7];
    const float* qw   = (const float*)d_in[8];
    const float* kw   = (const float*)d_in[9];
    const float* sink = (const float*)d_in[10];
    float* out = (float*)d_out;

    char* ws = (char*)d_ws;
    size_t off = 0;
    auto alloc = [&](size_t bytes) {
        char* p = ws + off;
        off += (bytes + 255) & ~(size_t)255;
        return p;
    };
    u16*   xb    = (u16*)alloc((size_t)2048 * 2048 * 2);
    u16*   wqkvt = (u16*)alloc((size_t)3072 * 2048 * 2);
    u16*   wot   = (u16*)alloc((size_t)2048 * 2048 * 2);
    float* qkv   = (float*)alloc((size_t)2048 * 3072 * 4);
    u16*   qnb   = (u16*)alloc((size_t)2048 * 2048 * 2);
    u16*   kfrag = (u16*)alloc((size_t)8 * 128 * 1024 * 2);
    u16*   vfrag = (u16*)alloc((size_t)8 * 128 * 1024 * 2);
    u16*   attnb = xb;  // reuse (xb dead after GEMM1)

    cast_bf16_k<<<2048, 256, 0, stream>>>(x, xb, 2048 * 2048 / 4);
    transpose_cast_k<<<dim3(32, 32), 256, 0, stream>>>(wq, wqkvt, 2048, 2048);
    transpose_cast_k<<<dim3(8, 32), 256, 0, stream>>>(wk, wqkvt + (size_t)2048 * 2048, 2048, 512);
    transpose_cast_k<<<dim3(8, 32), 256, 0, stream>>>(wv, wqkvt + (size_t)2560 * 2048, 2048, 512);
    transpose_cast_k<<<dim3(32, 32), 256, 0, stream>>>(wo, wot, 2048, 2048);

    gemm_bt_k<<<dim3(24, 16), 256, 0, stream>>>(xb, wqkvt, qkv, 2048, 3072, 2048);
    norm_rope_k<<<20480, 256, 0, stream>>>(qkv, cosb, sinb, qw, kw, qnb, kfrag);
    v_frag_k<<<dim3(32, 8), 256, 0, stream>>>(qkv, vfrag);
    attn_k<<<dim3(32, 32), 128, 0, stream>>>(qnb, kfrag, vfrag, sink, attnb);
    gemm_bt_k<<<dim3(16, 16), 256, 0, stream>>>(attnb, wot, out, 2048, 2048, 2048);
}

// Round 3
// 295.907 us; speedup vs baseline: 1.2000x; 1.0241x over previous
//
#include <hip/hip_runtime.h>

typedef unsigned short u16;
typedef __bf16 bf16;
typedef float f32x4 __attribute__((ext_vector_type(4)));
typedef bf16 bf16x8 __attribute__((ext_vector_type(8)));
typedef bf16 bf16x4 __attribute__((ext_vector_type(4)));
typedef short s16x4 __attribute__((ext_vector_type(4)));
typedef u16 u16x4 __attribute__((ext_vector_type(4)));

#define SEQ 2048
#define LOG2E 1.4426950408889634f

__device__ __forceinline__ u16 f2bf(float f) {
    return __builtin_bit_cast(u16, (bf16)f);
}

// ---------------- cast f32 -> bf16 (vectorized) ----------------
__global__ __launch_bounds__(256) void cast_bf16_k(const float* __restrict__ in,
                                                   u16* __restrict__ out, int n4) {
    int i = blockIdx.x * 256 + threadIdx.x;
    int stride = gridDim.x * 256;
    for (; i < n4; i += stride) {
        float4 v = reinterpret_cast<const float4*>(in)[i];
        u16x4 o;
        o[0] = f2bf(v.x); o[1] = f2bf(v.y); o[2] = f2bf(v.z); o[3] = f2bf(v.w);
        reinterpret_cast<u16x4*>(out)[i] = o;
    }
}

// ---------------- transpose + cast: src f32 [R][C] -> dst bf16 [C][R] ----------------
__global__ __launch_bounds__(256) void transpose_cast_k(const float* __restrict__ src,
                                                        u16* __restrict__ dst, int R, int C) {
    __shared__ float t[64][65];
    int c0 = blockIdx.x * 64, r0 = blockIdx.y * 64;
    int tx = threadIdx.x & 63, ty = threadIdx.x >> 6;
#pragma unroll
    for (int i = 0; i < 16; ++i) {
        int r = ty + i * 4;
        t[r][tx] = src[(size_t)(r0 + r) * C + c0 + tx];
    }
    __syncthreads();
#pragma unroll
    for (int i = 0; i < 16; ++i) {
        int c = ty + i * 4;
        dst[(size_t)(c0 + c) * R + r0 + tx] = f2bf(t[tx][c]);
    }
}

// ---------------- GEMM: C[M,N] = A[M,K] @ Bt[N,K]^T, bf16 in, f32 out ----------------
__global__ __launch_bounds__(256) void gemm_bt_k(const u16* __restrict__ A,
                                                 const u16* __restrict__ Bt,
                                                 float* __restrict__ C,
                                                 int M, int N, int K) {
    __shared__ __align__(16) u16 As[128 * 32];
    __shared__ __align__(16) u16 Bs[128 * 32];
    int tid = threadIdx.x;
    int wave = tid >> 6, lane = tid & 63;
    int bm = blockIdx.y * 128, bn = blockIdx.x * 128;
    int wm = (wave >> 1) * 64, wn = (wave & 1) * 64;
    int g = lane >> 4, cidx = lane & 15;
    f32x4 acc[4][4] = {};

    int srow = (lane >> 2);
    int skol = (lane & 3) * 8;

    for (int kt = 0; kt < K; kt += 32) {
#pragma unroll
        for (int j = 0; j < 2; ++j) {
            const u16* gp = A + (size_t)(bm + (wave * 2 + j) * 16 + srow) * K + kt + skol;
            __builtin_amdgcn_global_load_lds(
                (__attribute__((address_space(1))) void*)gp,
                (__attribute__((address_space(3))) void*)&As[(wave * 2 + j) * 512],
                16, 0, 0);
        }
#pragma unroll
        for (int j = 0; j < 2; ++j) {
            const u16* gp = Bt + (size_t)(bn + (wave * 2 + j) * 16 + srow) * K + kt + skol;
            __builtin_amdgcn_global_load_lds(
                (__attribute__((address_space(1))) void*)gp,
                (__attribute__((address_space(3))) void*)&Bs[(wave * 2 + j) * 512],
                16, 0, 0);
        }
        asm volatile("s_waitcnt vmcnt(0)" ::: "memory");
        __syncthreads();

        bf16x8 af[4], bfr[4];
#pragma unroll
        for (int mi = 0; mi < 4; ++mi)
            af[mi] = *reinterpret_cast<const bf16x8*>(&As[(wm + mi * 16 + cidx) * 32 + g * 8]);
#pragma unroll
        for (int ni = 0; ni < 4; ++ni)
            bfr[ni] = *reinterpret_cast<const bf16x8*>(&Bs[(wn + ni * 16 + cidx) * 32 + g * 8]);
#pragma unroll
        for (int mi = 0; mi < 4; ++mi)
#pragma unroll
            for (int ni = 0; ni < 4; ++ni)
                acc[mi][ni] = __builtin_amdgcn_mfma_f32_16x16x32_bf16(af[mi], bfr[ni], acc[mi][ni], 0, 0, 0);
        __syncthreads();
    }

#pragma unroll
    for (int mi = 0; mi < 4; ++mi) {
#pragma unroll
        for (int r = 0; r < 4; ++r) {
            int row = bm + wm + mi * 16 + g * 4 + r;
            float* cp = C + (size_t)row * N + bn + wn + cidx;
#pragma unroll
            for (int ni = 0; ni < 4; ++ni)
                cp[ni * 16] = acc[mi][ni][r];
        }
    }
}

// ---------------- RMSNorm + RoPE for Q and K heads ----------------
// Q: pre-scaled by 0.125*log2(e) (exp2-base softmax), row-major [s][32*64]
// K: written in MFMA A-fragment order kfrag[kvh][kb=s>>4][g=d>>3][c=s&15][e=d&7]
__global__ __launch_bounds__(256) void norm_rope_k(const float* __restrict__ qkv,
                                                   const float* __restrict__ cosb,
                                                   const float* __restrict__ sinb,
                                                   const float* __restrict__ qw,
                                                   const float* __restrict__ kw,
                                                   u16* __restrict__ qn,
                                                   u16* __restrict__ kfrag) {
    int idx = blockIdx.x * 4 + (threadIdx.x >> 6);
    int lane = threadIdx.x & 63;
    int s = idx / 40, hh = idx - s * 40;
    float val;
    if (hh < 32) val = qkv[(size_t)s * 3072 + hh * 64 + lane];
    else         val = qkv[(size_t)s * 3072 + 2048 + (hh - 32) * 64 + lane];
    float ss = val * val;
#pragma unroll
    for (int mm = 32; mm; mm >>= 1) ss += __shfl_xor(ss, mm);
    float w = (hh < 32) ? qw[lane] : kw[lane];
    float xn = val * rsqrtf(ss * (1.f / 64.f) + 1e-6f) * w;
    float part = __shfl_xor(xn, 32);
    float rot = (lane < 32) ? -part : part;
    float o = xn * cosb[s * 64 + lane] + rot * sinb[s * 64 + lane];
    if (hh < 32) {
        qn[(size_t)s * 2048 + hh * 64 + lane] = f2bf(o * (0.125f * LOG2E));
    } else {
        int h8 = hh - 32;
        kfrag[(((size_t)h8 * 128 + (s >> 4)) << 10) + (lane >> 3) * 128 + (s & 15) * 8 + (lane & 7)] = f2bf(o);
    }
}

// ---------------- V in packed PV A-fragment order ----------------
// vfrag[kvh][kb32][dt][g][c][s2*4+i] = V[kb32*32 + s2*16 + g*4 + i][dt*16 + c]
// -> one dwordx4 per lane covers two 16-key subtiles (lo/hi operand halves)
__global__ __launch_bounds__(256) void v_frag_k(const float* __restrict__ qkv,
                                                u16* __restrict__ vfrag) {
    __shared__ float t[64][65];
    int s0 = blockIdx.x * 64;
    int h = blockIdx.y;
    int tx = threadIdx.x & 63, ty = threadIdx.x >> 6;
#pragma unroll
    for (int i = 0; i < 16; ++i) {
        int r = ty + i * 4;
        t[r][tx] = qkv[(size_t)(s0 + r) * 3072 + 2560 + h * 64 + tx];
    }
    __syncthreads();
    int dt = threadIdx.x >> 6, g = (threadIdx.x >> 4) & 3, cc = threadIdx.x & 15;
#pragma unroll
    for (int kb2 = 0; kb2 < 4; ++kb2) {
        u16x4 o;
#pragma unroll
        for (int i = 0; i < 4; ++i) o[i] = f2bf(t[kb2 * 16 + g * 4 + i][dt * 16 + cc]);
        size_t idx = ((size_t)h * 64 + (s0 >> 5) + (kb2 >> 1)) * 2048 + dt * 512 + g * 128 + cc * 8 + (kb2 & 1) * 4;
        *reinterpret_cast<u16x4*>(&vfrag[idx]) = o;
    }
}

// ---------------- Flash attention, fixed-base softmax, key-window split ----------------
// grid (32 heads, 128 = 32 quads x 4 windows), block 256 = 4 waves.
// wave -> chunk c = 4*quad + wave (16 q rows), key window [w*512, w*512+512).
// Partial o (f32) and l accumulate into obuf/lbuf via HW f32 atomics; merge_k finishes.
__global__ __launch_bounds__(256, 4) void attn_k(const u16* __restrict__ qn,
                                                 const u16* __restrict__ kfrag,
                                                 const u16* __restrict__ vfrag,
                                                 float* __restrict__ obuf,
                                                 float* __restrict__ lbuf) {
    int h = blockIdx.x;
    int quad = blockIdx.y >> 2;
    int w = blockIdx.y & 3;
    int wave = threadIdx.x >> 6, lane = threadIdx.x & 63;
    int c = quad * 4 + wave;
    int q0 = c * 16;
    int nk = q0 + 16;
    int kv0 = w * 512;
    if (kv0 >= nk) return;
    int kvend = (kv0 + 512 < nk) ? (kv0 + 512) : nk;

    int kvh = h >> 2, g = lane >> 4, cc = lane & 15;
    int qrow = q0 + cc;

    const size_t qoff = (size_t)qrow * 2048 + h * 64;
    bf16x8 q_0 = *reinterpret_cast<const bf16x8*>(&qn[qoff + g * 8]);
    bf16x8 q_1 = *reinterpret_cast<const bf16x8*>(&qn[qoff + 32 + g * 8]);

    float l = 0.f;
    f32x4 o[4] = {};

    const u16* kbase = kfrag + (((size_t)kvh * 128) << 10) + lane * 8;
    const u16* vbase = vfrag + (size_t)kvh * 64 * 2048 + g * 128 + cc * 8;

    // preload K for first block
    bf16x8 kf0[4], kf1[4];
#pragma unroll
    for (int sub = 0; sub < 4; ++sub) {
        const u16* kp = kbase + (size_t)((kv0 >> 4) + sub) * 1024;
        kf0[sub] = *reinterpret_cast<const bf16x8*>(kp);
        kf1[sub] = *reinterpret_cast<const bf16x8*>(kp + 512);
    }

#pragma unroll 1
    for (; kv0 < kvend; kv0 += 64) {
        f32x4 st[4];
        __builtin_amdgcn_s_setprio(1);
#pragma unroll
        for (int sub = 0; sub < 4; ++sub) {
            st[sub] = __builtin_amdgcn_mfma_f32_16x16x32_bf16(kf0[sub], q_0, (f32x4){0.f, 0.f, 0.f, 0.f}, 0, 0, 0);
            st[sub] = __builtin_amdgcn_mfma_f32_16x16x32_bf16(kf1[sub], q_1, st[sub], 0, 0, 0);
        }
        __builtin_amdgcn_s_setprio(0);

        // K prefetch for next block (in-flight across softmax)
        if (kv0 + 64 < kvend) {
#pragma unroll
            for (int sub = 0; sub < 4; ++sub) {
                const u16* kp = kbase + (size_t)(((kv0 + 64) >> 4) + sub) * 1024;
                kf0[sub] = *reinterpret_cast<const bf16x8*>(kp);
                kf1[sub] = *reinterpret_cast<const bf16x8*>(kp + 512);
            }
        }

        // V loads for current block (issued before softmax VALU)
        bf16x8 vv[2][4];
#pragma unroll
        for (int sp = 0; sp < 2; ++sp)
#pragma unroll
            for (int dt = 0; dt < 4; ++dt)
                vv[sp][dt] = *reinterpret_cast<const bf16x8*>(
                    vbase + (size_t)((kv0 >> 5) + sp) * 2048 + dt * 512);

        // causal mask (diagonal block only)
        if (kv0 + 64 > q0) {
#pragma unroll
            for (int sub = 0; sub < 4; ++sub)
#pragma unroll
                for (int r = 0; r < 4; ++r)
                    if (kv0 + sub * 16 + g * 4 + r > qrow) st[sub][r] = -1e30f;
        }

        // fixed-base softmax: weights = exp2(score'), no max tracking
        s16x4 pf[4];
        float rs = 0.f;
#pragma unroll
        for (int sub = 0; sub < 4; ++sub)
#pragma unroll
            for (int r = 0; r < 4; ++r) {
                float e = exp2f(st[sub][r]);
                rs += e;
                pf[sub][r] = (short)f2bf(e);
            }
        l += rs;

        __builtin_amdgcn_s_setprio(1);
#pragma unroll
        for (int sp = 0; sp < 2; ++sp)
#pragma unroll
            for (int dt = 0; dt < 4; ++dt) {
                s16x4 vlo = __builtin_bit_cast(s16x4,
                    __builtin_shufflevector(vv[sp][dt], vv[sp][dt], 0, 1, 2, 3));
                s16x4 vhi = __builtin_bit_cast(s16x4,
                    __builtin_shufflevector(vv[sp][dt], vv[sp][dt], 4, 5, 6, 7));
                o[dt] = __builtin_amdgcn_mfma_f32_16x16x16bf16_1k(vlo, pf[sp * 2], o[dt], 0, 0, 0);
                o[dt] = __builtin_amdgcn_mfma_f32_16x16x16bf16_1k(vhi, pf[sp * 2 + 1], o[dt], 0, 0, 0);
            }
        __builtin_amdgcn_s_setprio(0);
    }

    // accumulate partials
    l += __shfl_xor(l, 16);
    l += __shfl_xor(l, 32);
    if (lane < 16) unsafeAtomicAdd(&lbuf[h * 2048 + qrow], l);
#pragma unroll
    for (int dt = 0; dt < 4; ++dt)
#pragma unroll
        for (int r = 0; r < 4; ++r)
            unsafeAtomicAdd(&obuf[(size_t)qrow * 2048 + h * 64 + dt * 16 + g * 4 + r], o[dt][r]);
}

// ---------------- merge: attn_bf16 = o / (l + 2^(sink*log2e)) ----------------
__global__ __launch_bounds__(256) void merge_k(const float* __restrict__ obuf,
                                               const float* __restrict__ lbuf,
                                               const float* __restrict__ sink,
                                               u16* __restrict__ attnb) {
    int row = blockIdx.x;
    int t = threadIdx.x;
#pragma unroll
    for (int j = 0; j < 2; ++j) {
        int col = j * 1024 + t * 4;
        int h = col >> 6;
        float lf = lbuf[h * 2048 + row] + exp2f(sink[h] * LOG2E);
        float inv = 1.f / lf;
        f32x4 ov = *reinterpret_cast<const f32x4*>(&obuf[(size_t)row * 2048 + col]);
        u16x4 ob;
#pragma unroll
        for (int i = 0; i < 4; ++i) ob[i] = f2bf(ov[i] * inv);
        *reinterpret_cast<u16x4*>(&attnb[(size_t)row * 2048 + col]) = ob;
    }
}

extern "C" void kernel_launch(void* const* d_in, const int* in_sizes, int n_in,
                              void* d_out, int out_size, void* d_ws, size_t ws_size,
                              hipStream_t stream) {
    const float* x    = (const float*)d_in[0];
    const float* cosb = (const float*)d_in[2];
    const float* sinb = (const float*)d_in[3];
    const float* wq   = (const float*)d_in[4];
    const float* wk   = (const float*)d_in[5];
    const float* wv   = (const float*)d_in[6];
    const float* wo   = (const float*)d_in[7];
    const float* qw   = (const float*)d_in[8];
    const float* kw   = (const float*)d_in[9];
    const float* sink = (const float*)d_in[10];
    float* out = (float*)d_out;

    char* ws = (char*)d_ws;
    size_t off = 0;
    auto alloc = [&](size_t bytes) {
        char* p = ws + off;
        off += (bytes + 255) & ~(size_t)255;
        return p;
    };
    u16*   xb    = (u16*)alloc((size_t)2048 * 2048 * 2);
    u16*   wqkvt = (u16*)alloc((size_t)3072 * 2048 * 2);
    u16*   wot   = (u16*)alloc((size_t)2048 * 2048 * 2);
    float* qkv   = (float*)alloc((size_t)2048 * 3072 * 4);
    u16*   qnb   = (u16*)alloc((size_t)2048 * 2048 * 2);
    u16*   kfrag = (u16*)alloc((size_t)8 * 128 * 1024 * 2);
    u16*   vfrag = (u16*)alloc((size_t)8 * 64 * 2048 * 2);
    u16*   attnb = xb;                         // xb dead after GEMM1
    float* obuf  = qkv;                        // qkv dead after norm_rope/v_frag
    float* lbuf  = qkv + (size_t)2048 * 2048;  // 32*2048 f32, right after obuf

    cast_bf16_k<<<2048, 256, 0, stream>>>(x, xb, 2048 * 2048 / 4);
    transpose_cast_k<<<dim3(32, 32), 256, 0, stream>>>(wq, wqkvt, 2048, 2048);
    transpose_cast_k<<<dim3(8, 32), 256, 0, stream>>>(wk, wqkvt + (size_t)2048 * 2048, 2048, 512);
    transpose_cast_k<<<dim3(8, 32), 256, 0, stream>>>(wv, wqkvt + (size_t)2560 * 2048, 2048, 512);
    transpose_cast_k<<<dim3(32, 32), 256, 0, stream>>>(wo, wot, 2048, 2048);

    gemm_bt_k<<<dim3(24, 16), 256, 0, stream>>>(xb, wqkvt, qkv, 2048, 3072, 2048);
    norm_rope_k<<<20480, 256, 0, stream>>>(qkv, cosb, sinb, qw, kw, qnb, kfrag);
    v_frag_k<<<dim3(32, 8), 256, 0, stream>>>(qkv, vfrag);

    hipMemsetAsync(obuf, 0, ((size_t)2048 * 2048 + 32 * 2048) * sizeof(float), stream);
    attn_k<<<dim3(32, 128), 256, 0, stream>>>(qnb, kfrag, vfrag, obuf, lbuf);
    merge_k<<<2048, 256, 0, stream>>>(obuf, lbuf, sink, attnb);

    gemm_bt_k<<<dim3(16, 16), 256, 0, stream>>>(attnb, wot, out, 2048, 2048, 2048);
}